// Round 12
// baseline (229.857 us; speedup 1.0000x reference)
//
#include <hip/hip_runtime.h>

// H2G2: 2-layer RGCN (R=4, per-relation mean) + mean-pool + linear.
// R10 (231us, layer 47): register-resident fused layer. R11 FAILED: VGPR cap
//   -> scratch spill. R12 (229.6): channel-split wave pair; layer pinned 47.0.
// R13 FAILED: random 4B global writes = line RMW. R14 FAILED: grid.sync
//   ~80-90us each w/ idle grid. R15: CAP-bucket OK; per-element device
//   atomics FAILED. R16 (219.6): 6-dispatch pipeline, layers 47.0.
// R17 FAILED: 8-edge unroll -> VGPR 140 -> occ crash (MLP: fewer lines in
//   flight). R18 (275): LDS-first pooling OK; 1-block uncached cls = 70us
//   serial tail. R19 (232.4): in-layer CSR paid twice. R20 (218.3, BEST):
//   CSR built once in layer_build (62 = 47 gather + 15 PhaseA), persisted.
// R21 NULL (219.7): read at 32 waves/CU (128thr/3125blk) == 24 waves/CU.
//   With R17: gather saturates a per-XCD RANDOM-FILL RATE ~0.9 lines/cy at
//   >=96 lines/CU in flight. Gather = HW roofline 47us/layer. FROZEN.
//   fp8 would halve it but e4m3 2^-4 rel err likely busts absmax. Not taken.
// R22: attack PhaseA's 15us: it is tmp L2-FILL (each build block over-reads
//   its 256-node bucket 8x; ~3MB/XCD cold fill at 0.9 lines/cy ~= 15us),
//   not scan compute (~0.25us/block). Fix: bin emits 64-node sub-buckets
//   (782 bins, CAP2=1280, payload src<<8|et<<6|dl6) -> build over-reads 2x
//   (~0.8MB/XCD ~= 5us). PhaseA scans int4-vectorized (tmp +4KB pad).
//   read reverted to R20 256-thr. Watch: reserve atomics 100k->283k in work.

#define RR 4
#define HH 64
#define KK 320         // (RR+1)*HH
#define LWN (HH * KK)  // weights per layer = 20480
#define EPB 2048       // edges per bin chunk
#define CAP2 1280      // per-64-node-bucket capacity (mean 1024, +8 sigma)
#define NSLOT 8        // LDS pool slots
#define VCAP 1024      // per-build-block edge list cap (mean 512, +22 sigma)

using frag_ab = __attribute__((ext_vector_type(8))) short;
using frag_cd = __attribute__((ext_vector_type(4))) float;

__device__ inline short f2bf(float f) {
    unsigned u = __builtin_bit_cast(unsigned, f);
    unsigned r = u + 0x7fffu + ((u >> 16) & 1u);  // RNE
    return (short)(r >> 16);
}
__device__ inline float bf2f(short s) {
    unsigned u = ((unsigned)(unsigned short)s) << 16;
    return __builtin_bit_cast(float, u);
}

// ---- shared gather accumulate macro ----
#define ACCM(P, F)                                                            \
    {                                                                         \
        int r_ = (P) & 3;                                                     \
        float s0_ = (r_ == 0) ? 1.f : 0.f;                                    \
        float s1_ = (r_ == 1) ? 1.f : 0.f;                                    \
        float s2_ = (r_ == 2) ? 1.f : 0.f;                                    \
        float s3_ = (r_ == 3) ? 1.f : 0.f;                                    \
        _Pragma("unroll") for (int j = 0; j < 8; ++j) {                       \
            float v_ = bf2f((F)[j]);                                          \
            acc[0][j] += v_ * s0_;                                            \
            acc[1][j] += v_ * s1_;                                            \
            acc[2][j] += v_ * s2_;                                            \
            acc[3][j] += v_ * s3_;                                            \
        }                                                                     \
    }

// ---- work: bin(64-node bins) | weights | gstart | gsum-zero | x conv ----
__global__ __launch_bounds__(256) void work_kernel(
    const int* __restrict__ src, const int* __restrict__ dst,
    const int* __restrict__ et, int E,
    int* __restrict__ cur, int* __restrict__ tmp,
    const float* __restrict__ basis1, const float* __restrict__ comp1, const float* __restrict__ root1,
    const float* __restrict__ basis2, const float* __restrict__ comp2, const float* __restrict__ root2,
    short* __restrict__ W1t, short* __restrict__ W2t,
    const int* __restrict__ batch, int* __restrict__ gstart, int N, int G,
    const float* __restrict__ x, short* __restrict__ Xb,
    float* __restrict__ gsum,
    int ebl, int wbl, int nb, int gzb) {
    __shared__ int lc[1024];      // 64-node-bin counts (782 used, pad 0)
    __shared__ int lscan[1024];   // staged prefix per bin
    __shared__ int lbase[1024];   // reserved global base per bin
    __shared__ int lc2[1024];     // staging cursors
    __shared__ int ss[256];
    __shared__ int sbuf[EPB];
    const int bid = blockIdx.x;
    const int t = threadIdx.x;

    if (bid < ebl) {  // ---- bin: LDS-staged scatter into 64-node CAP2 regions ----
        const int e0 = bid * EPB;
        const int e1 = min(e0 + EPB, E);
        for (int i = t; i < 1024; i += 256) lc[i] = 0;
        __syncthreads();
        for (int e = e0 + t; e < e1; e += 256) atomicAdd(&lc[dst[e] >> 6], 1);
        __syncthreads();
        int c0 = lc[t * 4], c1 = lc[t * 4 + 1], c2 = lc[t * 4 + 2], c3 = lc[t * 4 + 3];
        int sum = c0 + c1 + c2 + c3;
        ss[t] = sum;
        __syncthreads();
#pragma unroll
        for (int off = 1; off < 256; off <<= 1) {
            int u = (t >= off) ? ss[t - off] : 0;
            __syncthreads();
            ss[t] += u;
            __syncthreads();
        }
        int base = ss[t] - sum;
        lscan[t * 4]     = base;
        lscan[t * 4 + 1] = base + c0;
        lscan[t * 4 + 2] = base + c0 + c1;
        lscan[t * 4 + 3] = base + c0 + c1 + c2;
        // reserve global space per bin + init cursors
#pragma unroll
        for (int q = 0; q < 4; ++q) {
            int bn = t * 4 + q;
            int cv = lc[bn];
            lbase[bn] = cv ? bn * CAP2 + atomicAdd(&cur[bn], cv) : 0;
            lc2[bn] = 0;
        }
        __syncthreads();
        for (int e = e0 + t; e < e1; e += 256) {
            int d = dst[e];
            int bn = d >> 6;
            int p = (src[e] << 8) | (et[e] << 6) | (d & 63);
            int pos = lscan[bn] + atomicAdd(&lc2[bn], 1);
            sbuf[pos] = p;
        }
        __syncthreads();
        int tot = e1 - e0;
        for (int i = t; i < tot; i += 256) {
            int lo = 0, hi = 1023;
            while (lo < hi) { int mid = (lo + hi + 1) >> 1; if (lscan[mid] <= i) lo = mid; else hi = mid - 1; }
            int idx = lbase[lo] + (i - lscan[lo]);
            if (idx - lo * CAP2 < CAP2) tmp[idx] = sbuf[i];  // overflow shield
        }
    } else if (bid < ebl + wbl) {  // ---- weights: Wt[c*320+k] = Wstack[k][c] ----
        int w = (bid - ebl) * 256 + t;
        int layer = w / LWN;
        int rem = w - layer * LWN;
        int c = rem / KK;
        int k = rem - c * KK;
        const float* basis = layer ? basis2 : basis1;
        const float* comp  = layer ? comp2  : comp1;
        const float* root  = layer ? root2  : root1;
        short* Wt          = layer ? W2t    : W1t;
        float v;
        if (k < HH) {
            v = root[k * HH + c];
        } else {
            int r = (k >> 6) - 1, kk = k & 63;
            v = 0.f;
#pragma unroll
            for (int b = 0; b < RR; ++b) v += comp[r * RR + b] * basis[(b * HH + kk) * HH + c];
        }
        Wt[c * KK + k] = f2bf(v);
    } else if (bid < ebl + wbl + nb) {  // ---- gstart ----
        int i = (bid - ebl - wbl) * 256 + t;
        if (i < N) {
            int b1 = batch[i];
            int b0 = (i == 0) ? -1 : batch[i - 1];
            for (int g = b0 + 1; g <= b1; ++g) gstart[g] = i;
            if (i == N - 1)
                for (int g = b1 + 1; g <= G; ++g) gstart[g] = N;
        }
    } else if (bid < ebl + wbl + nb + gzb) {  // ---- zero gsum (float4) ----
        int i4 = (bid - ebl - wbl - nb) * 256 + t;
        if (i4 < G * (HH / 4))
            *(float4*)&gsum[i4 * 4] = make_float4(0.f, 0.f, 0.f, 0.f);
    } else {  // ---- convert x fp32 -> bf16 ----
        int i4 = (bid - ebl - wbl - nb - gzb) * 256 + t;
        int base = i4 * 4;
        if (base < N * 64) {
            float4 f = *(const float4*)&x[base];
            short4 s;
            s.x = f2bf(f.x); s.y = f2bf(f.y); s.z = f2bf(f.z); s.w = f2bf(f.w);
            *(short4*)&Xb[base] = s;
        }
    }
}

// ---- layer_build (L1, 256 thr / 32 nodes): Phase A CSR from 64-node bucket
//      (int4 scans, 2x over-read) -> persist rp4/kend/eidxg; Phase B = FROZEN
//      4-deep gather from LDS elist. ----
__global__ __launch_bounds__(256) void layer_build_kernel(
    const int* __restrict__ curg,
    const int* __restrict__ tmp,
    const short* __restrict__ Xb,
    const short* __restrict__ Wt,
    const float* __restrict__ bias,
    short* __restrict__ out, int n,
    int4* __restrict__ rp4g, int* __restrict__ kendg,
    int* __restrict__ eidxg) {
    __shared__ short xpack[2][64][32];  // 8KB
    __shared__ int cnt[128];
    __shared__ int off[129];
    __shared__ int curs[128];
    __shared__ int elist[VCAP];         // 4KB
    const int t = threadIdx.x;
    const int wv = t >> 6;
    const int pair = wv >> 1;
    const int ws = wv & 1;
    const int l = t & 63;
    const int m = l & 15;
    const int quad = l >> 4;
    const int node0 = blockIdx.x * 32;
    const int node = node0 + pair * 16 + m;
    const bool valid = node < n;

    // ---- Phase A (64-node bucket, int4 scans) ----
    const int b2 = node0 >> 6;
    const int dl0 = node0 & 63;  // 0 or 32
    const int tb = b2 * CAP2;
    const int len = min(curg[b2], CAP2);

    for (int i = t; i < 128; i += 256) cnt[i] = 0;
    __syncthreads();
    for (int i4 = t * 4; i4 < len; i4 += 1024) {
        int4 e4 = *(const int4*)&tmp[tb + i4];  // tmp padded: safe tail read
        int ec[4] = {e4.x, e4.y, e4.z, e4.w};
#pragma unroll
        for (int c = 0; c < 4; ++c) {
            if (i4 + c < len) {
                int e = ec[c];
                int w = (e & 63) - dl0;
                if ((unsigned)w < 32u) atomicAdd(&cnt[(w << 2) | ((e >> 6) & 3)], 1);
            }
        }
    }
    __syncthreads();
    if (t < 128) off[t] = cnt[t];
    __syncthreads();
#pragma unroll
    for (int o = 1; o < 128; o <<= 1) {
        int u = (t < 128 && t >= o) ? off[t - o] : 0;
        __syncthreads();
        if (t < 128) off[t] += u;
        __syncthreads();
    }
    if (t < 128) {
        int ex = off[t] - cnt[t];
        off[t] = ex;
        curs[t] = ex;
        if (t == 127) off[128] = ex + cnt[127];
    }
    __syncthreads();
    for (int i4 = t * 4; i4 < len; i4 += 1024) {
        int4 e4 = *(const int4*)&tmp[tb + i4];
        int ec[4] = {e4.x, e4.y, e4.z, e4.w};
#pragma unroll
        for (int c = 0; c < 4; ++c) {
            if (i4 + c < len) {
                int e = ec[c];
                int w = (e & 63) - dl0;
                if ((unsigned)w < 32u) {
                    int pos = atomicAdd(&curs[(w << 2) | ((e >> 6) & 3)], 1);
                    if (pos < VCAP) elist[pos] = ((e >> 8) << 2) | ((e >> 6) & 3);
                }
            }
        }
    }
    __syncthreads();

    // ---- persist CSR (overlaps with Phase B issue) ----
    const int eb = blockIdx.x * VCAP;
    if (t < 32 && node0 + t < n) {
        int c4 = t << 2;
        rp4g[node0 + t] = make_int4(eb + min(off[c4], VCAP), eb + min(off[c4 + 1], VCAP),
                                    eb + min(off[c4 + 2], VCAP), eb + min(off[c4 + 3], VCAP));
        kendg[node0 + t] = eb + min(off[c4 + 4], VCAP);
    }
    {
        int fill = min(off[128], VCAP);
        for (int i = t; i < fill; i += 256) eidxg[eb + i] = elist[i];
    }

    // ---- Phase B: FROZEN gather from LDS elist ----
    float acc[4][8];
#pragma unroll
    for (int r = 0; r < 4; ++r)
#pragma unroll
        for (int j = 0; j < 8; ++j) acc[r][j] = 0.f;

    const int w4 = ((pair << 4) | m) << 2;
    const int k0 = min(off[w4], VCAP);
    const int k1 = min(off[w4 + 4], VCAP);
    float4 iv;
    iv.x = 1.0f / fmaxf((float)cnt[w4 + 0], 1.0f);
    iv.y = 1.0f / fmaxf((float)cnt[w4 + 1], 1.0f);
    iv.z = 1.0f / fmaxf((float)cnt[w4 + 2], 1.0f);
    iv.w = 1.0f / fmaxf((float)cnt[w4 + 3], 1.0f);
    const short* xbq = Xb + ws * 32 + quad * 8;

    int k = k0;
    for (; k + 3 < k1; k += 4) {
        int p0 = elist[k];
        int p1 = elist[k + 1];
        int p2 = elist[k + 2];
        int p3 = elist[k + 3];
        const short* a0p = xbq + (size_t)(p0 >> 2) * 64;
        const short* a1p = xbq + (size_t)(p1 >> 2) * 64;
        const short* a2p = xbq + (size_t)(p2 >> 2) * 64;
        const short* a3p = xbq + (size_t)(p3 >> 2) * 64;
        frag_ab f0 = *(const frag_ab*)a0p;
        frag_ab f1 = *(const frag_ab*)a1p;
        frag_ab f2 = *(const frag_ab*)a2p;
        frag_ab f3 = *(const frag_ab*)a3p;
        ACCM(p0, f0)
        ACCM(p1, f1)
        ACCM(p2, f2)
        ACCM(p3, f3)
    }
    for (; k < k1; ++k) {
        int p0 = elist[k];
        const short* a0p = xbq + (size_t)(p0 >> 2) * 64;
        frag_ab f0 = *(const frag_ab*)a0p;
        ACCM(p0, f0)
    }

    frag_ab y[4];
    {
        float s0 = iv.x, s1 = iv.y, s2 = iv.z, s3 = iv.w;
#pragma unroll
        for (int j = 0; j < 8; ++j) {
            y[0][j] = f2bf(acc[0][j] * s0);
            y[1][j] = f2bf(acc[1][j] * s1);
            y[2][j] = f2bf(acc[2][j] * s2);
            y[3][j] = f2bf(acc[3][j] * s3);
        }
    }

    if (ws == 1) {
#pragma unroll
        for (int r = 0; r < 4; ++r)
            *(frag_ab*)&xpack[pair][l][r * 8] = y[r];
    }
    __syncthreads();
    if (ws == 1) return;

    frag_ab a[10];
    a[0] = frag_ab{};
    a[1] = frag_ab{};
    if (valid) {
        const short* xr = Xb + (size_t)node * 64 + quad * 8;
        a[0] = *(const frag_ab*)xr;
        a[1] = *(const frag_ab*)(xr + 32);
    }
#pragma unroll
    for (int r = 0; r < 4; ++r) {
        a[2 + 2 * r] = y[r];
        a[3 + 2 * r] = *(const frag_ab*)&xpack[pair][l][r * 8];
    }

    const int nrow_base = node0 + pair * 16 + quad * 4;
#pragma unroll
    for (int ct = 0; ct < 4; ++ct) {
        const short* bp = Wt + (size_t)(ct * 16 + m) * KK + quad * 8;
        frag_cd c = {0.f, 0.f, 0.f, 0.f};
#pragma unroll
        for (int f = 0; f < 10; ++f) {
            frag_ab bf = *(const frag_ab*)(bp + f * 32);
            c = __builtin_amdgcn_mfma_f32_16x16x32_bf16(a[f], bf, c, 0, 0, 0);
        }
        int col = ct * 16 + m;
        float bv = bias[col];
#pragma unroll
        for (int r = 0; r < 4; ++r) {
            int nr = nrow_base + r;
            if (nr < n) out[(size_t)nr * 64 + col] = f2bf(fmaxf(c[r] + bv, 0.f));
        }
    }
}

// ---- layer_read (L2, R20 config: 256 thr / 32 nodes): gather from persisted
//      CSR + LDS-first pooling -> gsum. ----
__global__ __launch_bounds__(256) void layer_read_kernel(
    const int4* __restrict__ rp4g, const int* __restrict__ kendg,
    const int* __restrict__ eidxg,
    const short* __restrict__ Xb,
    const short* __restrict__ Wt,
    const float* __restrict__ bias,
    int n, const int* __restrict__ batch, float* __restrict__ gsum) {
    __shared__ short xpack[2][64][32];  // 8KB
    __shared__ float pgs[NSLOT * 64];   // 2KB
    const int t = threadIdx.x;
    const int wv = t >> 6;
    const int pair = wv >> 1;
    const int ws = wv & 1;
    const int l = t & 63;
    const int m = l & 15;
    const int quad = l >> 4;
    const int node0 = blockIdx.x * 32;
    const int node = node0 + pair * 16 + m;
    const bool valid = node < n;

    for (int i = t; i < NSLOT * 64; i += 256) pgs[i] = 0.f;

    float acc[4][8];
#pragma unroll
    for (int r = 0; r < 4; ++r)
#pragma unroll
        for (int j = 0; j < 8; ++j) acc[r][j] = 0.f;

    int k0 = 0, k1 = 0;
    float4 iv = make_float4(0.f, 0.f, 0.f, 0.f);
    if (valid) {
        int4 r4 = rp4g[node];
        int kend = kendg[node];
        k0 = r4.x;
        k1 = kend;
        iv.x = 1.0f / fmaxf((float)(r4.y - r4.x), 1.0f);
        iv.y = 1.0f / fmaxf((float)(r4.z - r4.y), 1.0f);
        iv.z = 1.0f / fmaxf((float)(r4.w - r4.z), 1.0f);
        iv.w = 1.0f / fmaxf((float)(kend - r4.w), 1.0f);
    }
    const short* xbq = Xb + ws * 32 + quad * 8;

    int k = k0;
    for (; k + 3 < k1; k += 4) {  // FROZEN 4-deep
        int p0 = eidxg[k];
        int p1 = eidxg[k + 1];
        int p2 = eidxg[k + 2];
        int p3 = eidxg[k + 3];
        const short* a0p = xbq + (size_t)(p0 >> 2) * 64;
        const short* a1p = xbq + (size_t)(p1 >> 2) * 64;
        const short* a2p = xbq + (size_t)(p2 >> 2) * 64;
        const short* a3p = xbq + (size_t)(p3 >> 2) * 64;
        frag_ab f0 = *(const frag_ab*)a0p;
        frag_ab f1 = *(const frag_ab*)a1p;
        frag_ab f2 = *(const frag_ab*)a2p;
        frag_ab f3 = *(const frag_ab*)a3p;
        ACCM(p0, f0)
        ACCM(p1, f1)
        ACCM(p2, f2)
        ACCM(p3, f3)
    }
    for (; k < k1; ++k) {
        int p0 = eidxg[k];
        const short* a0p = xbq + (size_t)(p0 >> 2) * 64;
        frag_ab f0 = *(const frag_ab*)a0p;
        ACCM(p0, f0)
    }

    frag_ab y[4];
    {
        float s0 = iv.x, s1 = iv.y, s2 = iv.z, s3 = iv.w;
#pragma unroll
        for (int j = 0; j < 8; ++j) {
            y[0][j] = f2bf(acc[0][j] * s0);
            y[1][j] = f2bf(acc[1][j] * s1);
            y[2][j] = f2bf(acc[2][j] * s2);
            y[3][j] = f2bf(acc[3][j] * s3);
        }
    }

    if (ws == 1) {
#pragma unroll
        for (int r = 0; r < 4; ++r)
            *(frag_ab*)&xpack[pair][l][r * 8] = y[r];
    }
    __syncthreads();

    const int nrow_base = node0 + pair * 16 + quad * 4;
    const int batch_base = batch[node0];

    if (ws == 0) {
        frag_ab a[10];
        a[0] = frag_ab{};
        a[1] = frag_ab{};
        if (valid) {
            const short* xr = Xb + (size_t)node * 64 + quad * 8;
            a[0] = *(const frag_ab*)xr;
            a[1] = *(const frag_ab*)(xr + 32);
        }
#pragma unroll
        for (int r = 0; r < 4; ++r) {
            a[2 + 2 * r] = y[r];
            a[3 + 2 * r] = *(const frag_ab*)&xpack[pair][l][r * 8];
        }

        int bv4[4];
        if (nrow_base + 3 < n) {
            int4 bb = *(const int4*)&batch[nrow_base];
            bv4[0] = bb.x; bv4[1] = bb.y; bv4[2] = bb.z; bv4[3] = bb.w;
        } else {
#pragma unroll
            for (int r = 0; r < 4; ++r)
                bv4[r] = (nrow_base + r < n) ? batch[nrow_base + r] : 0;
        }

#pragma unroll
        for (int ct = 0; ct < 4; ++ct) {
            const short* bp = Wt + (size_t)(ct * 16 + m) * KK + quad * 8;
            frag_cd c = {0.f, 0.f, 0.f, 0.f};
#pragma unroll
            for (int f = 0; f < 10; ++f) {
                frag_ab bf = *(const frag_ab*)(bp + f * 32);
                c = __builtin_amdgcn_mfma_f32_16x16x32_bf16(a[f], bf, c, 0, 0, 0);
            }
            int col = ct * 16 + m;
            float bv = bias[col];
#pragma unroll
            for (int r = 0; r < 4; ++r) {
                int nr = nrow_base + r;
                if (nr < n) {
                    float v = fmaxf(c[r] + bv, 0.f);
                    int g = bv4[r] - batch_base;
                    if (g < NSLOT)
                        atomicAdd(&pgs[g * 64 + col], v);
                    else
                        atomicAdd(&gsum[(size_t)bv4[r] * 64 + col], v);
                }
            }
        }
    }

    __syncthreads();
    int node_last = min(node0 + 31, n - 1);
    int gspan = batch[node_last] - batch_base;
    for (int i = t; i < NSLOT * 64; i += 256) {
        int s = i >> 6;
        if (s <= gspan) {
            float v = pgs[i];
            if (v != 0.f) atomicAdd(&gsum[(size_t)(batch_base + s) * 64 + (i & 63)], v);
        }
    }
}

// ---- cls: mean + linear from gsum (normal loads; kernel boundary = coherence) ----
__global__ __launch_bounds__(256) void cls_kernel(const float* __restrict__ gsum,
                                                  const int* __restrict__ gstart,
                                                  const float* __restrict__ w,
                                                  const float* __restrict__ bcls,
                                                  float* __restrict__ out, int G) {
    const int g = blockIdx.x * 256 + threadIdx.x;
    if (g >= G) return;
    int s = gstart[g], e = gstart[g + 1];
    float invc = 1.0f / fmaxf((float)(e - s), 1.0f);
    float o0 = 0.f, o1 = 0.f, o2 = 0.f, o3 = 0.f;
    const float* gr = gsum + (size_t)g * 64;
#pragma unroll 8
    for (int hh = 0; hh < 64; ++hh) {
        float mm = gr[hh] * invc;
        float4 wr = *(const float4*)&w[hh * 4];
        o0 += mm * wr.x;
        o1 += mm * wr.y;
        o2 += mm * wr.z;
        o3 += mm * wr.w;
    }
    float4 o = make_float4(o0 + bcls[0], o1 + bcls[1], o2 + bcls[2], o3 + bcls[3]);
    *(float4*)&out[g * 4] = o;
}

extern "C" void kernel_launch(void* const* d_in, const int* in_sizes, int n_in,
                              void* d_out, int out_size, void* d_ws, size_t ws_size,
                              hipStream_t stream) {
    const float* x        = (const float*)d_in[0];
    const int* edge_index = (const int*)d_in[1];
    const int* edge_type  = (const int*)d_in[2];
    const int* batch      = (const int*)d_in[3];
    const float* basis1 = (const float*)d_in[4];
    const float* comp1  = (const float*)d_in[5];
    const float* root1  = (const float*)d_in[6];
    const float* bias1  = (const float*)d_in[7];
    const float* basis2 = (const float*)d_in[8];
    const float* comp2  = (const float*)d_in[9];
    const float* root2  = (const float*)d_in[10];
    const float* bias2  = (const float*)d_in[11];
    const float* clas_w = (const float*)d_in[12];
    const float* clas_b = (const float*)d_in[13];

    const int N = in_sizes[0] / 64;
    const int E = in_sizes[2];
    const int G = out_size / 4;
    const int* src = edge_index;
    const int* dst = edge_index + E;
    const int nbuck2 = (N + 63) >> 6;          // 64-node buckets (782)
    const int build_blocks = (N + 31) / 32;
    const int read_blocks  = (N + 31) / 32;

    char* base = (char*)d_ws;
    size_t off = 0;
    auto carve = [&](size_t bytes) { void* p = base + off; off = (off + bytes + 15) & ~(size_t)15; return p; };
    int*   cur     = (int*)carve(sizeof(int) * (size_t)nbuck2);
    float* gsum    = (float*)carve(sizeof(float) * (size_t)G * HH);
    int*   gstart  = (int*)carve(sizeof(int) * ((size_t)G + 1));
    int*   tmp     = (int*)carve(sizeof(int) * ((size_t)nbuck2 * CAP2 + 1024));  // +pad for int4 tails
    int4*  rp4g    = (int4*)carve(sizeof(int4) * (size_t)N);
    int*   kendg   = (int*)carve(sizeof(int) * (size_t)N);
    int*   eidxg   = (int*)carve(sizeof(int) * (size_t)build_blocks * VCAP);
    short* W1t     = (short*)carve(sizeof(short) * LWN);
    short* W2t     = (short*)carve(sizeof(short) * LWN);
    short* Xb1     = (short*)carve(sizeof(short) * (size_t)N * 64);
    short* H1      = (short*)carve(sizeof(short) * (size_t)N * 64);
    float* gout    = (float*)d_out;

    const int ebl = (E + EPB - 1) / EPB;
    const int wbl = (2 * LWN + 255) / 256;
    const int nb  = (N + 255) / 256;
    const int gzb = (G * (HH / 4) + 255) / 256;
    const int cvb = (N * 64 / 4 + 255) / 256;
    const int work_blocks = ebl + wbl + nb + gzb + cvb;

    hipMemsetAsync(cur, 0, sizeof(int) * (size_t)nbuck2, stream);

    work_kernel<<<work_blocks, 256, 0, stream>>>(
        src, dst, edge_type, E, cur, tmp,
        basis1, comp1, root1, basis2, comp2, root2, W1t, W2t,
        batch, gstart, N, G, x, Xb1, gsum, ebl, wbl, nb, gzb);

    layer_build_kernel<<<build_blocks, 256, 0, stream>>>(
        cur, tmp, Xb1, W1t, bias1, H1, N, rp4g, kendg, eidxg);
    layer_read_kernel<<<read_blocks, 256, 0, stream>>>(
        rp4g, kendg, eidxg, H1, W2t, bias2, N, batch, gsum);

    cls_kernel<<<(G + 255) / 256, 256, 0, stream>>>(
        gsum, gstart, clas_w, clas_b, gout, G);
}

// Round 13
// 219.365 us; speedup vs baseline: 1.0478x; 1.0478x over previous
//
#include <hip/hip_runtime.h>

// H2G2: 2-layer RGCN (R=4, per-relation mean) + mean-pool + linear.
// R10 (231us, layer 47): register-resident fused layer. R11 FAILED: VGPR cap
//   -> scratch spill. R12 (229.6): channel-split wave pair; layer pinned 47.0.
// R13 FAILED: random 4B global writes = line RMW. R14 FAILED: grid.sync
//   ~80-90us each w/ idle grid. R15: CAP-bucket OK; per-element device
//   atomics FAILED. R16 (219.6): 6-dispatch pipeline, layers 47.0.
// R17 FAILED: 8-edge unroll -> VGPR 140 -> occ crash. MLP model: layer time
//   ~ 1/(waves x depth) until ~96 lines/CU, then per-XCD random-fill-rate
//   floor ~0.9 lines/cy (R21 null at 32 waves/CU proves rate-, not MSHR-,
//   bound). Gather FROZEN 4-deep. FETCH 52MB compulsory.
// R18 (275): LDS-first pooling OK; 1-block uncached cls = 70us serial tail.
// R19 (232.4): in-layer CSR paid twice. R20 (218.3, BEST): CSR once in
//   layer_build (62 = 47 gather + 15 PhaseA-tmp-fill), persisted.
// R22 (229.9): 64-node bins CONFIRMED PhaseA=tmp-fill (build 62->~50) but
//   bin's scatter became 2.6 edges/bin = random-4B-write RMW (work 51us,
//   WRITE 19MB). Fine bins trade build fill for bin coalescing. REVERTED.
// R23: same fill reduction, zero bin cost: XCD-aware bijective swizzle
//   (m204) on build's block->chunk map. The 8 blocks sharing a 256-node
//   bucket become same-XCD -> bucket filled into ONE L2 not 8 (per-XCD tmp
//   fill 3.2MB -> 0.4MB). Everything else = R20.

#define RR 4
#define HH 64
#define KK 320         // (RR+1)*HH
#define LWN (HH * KK)  // weights per layer = 20480
#define EPB 2048       // edges per bin chunk
#define CAP 6144       // per-256-node-bucket capacity (mean 4096, +32 sigma)
#define NSLOT 8        // LDS pool slots
#define VCAP 1024      // per-build-block edge list cap (mean 512, +22 sigma)

using frag_ab = __attribute__((ext_vector_type(8))) short;
using frag_cd = __attribute__((ext_vector_type(4))) float;

__device__ inline short f2bf(float f) {
    unsigned u = __builtin_bit_cast(unsigned, f);
    unsigned r = u + 0x7fffu + ((u >> 16) & 1u);  // RNE
    return (short)(r >> 16);
}
__device__ inline float bf2f(short s) {
    unsigned u = ((unsigned)(unsigned short)s) << 16;
    return __builtin_bit_cast(float, u);
}

// ---- shared gather accumulate macro ----
#define ACCM(P, F)                                                            \
    {                                                                         \
        int r_ = (P) & 3;                                                     \
        float s0_ = (r_ == 0) ? 1.f : 0.f;                                    \
        float s1_ = (r_ == 1) ? 1.f : 0.f;                                    \
        float s2_ = (r_ == 2) ? 1.f : 0.f;                                    \
        float s3_ = (r_ == 3) ? 1.f : 0.f;                                    \
        _Pragma("unroll") for (int j = 0; j < 8; ++j) {                       \
            float v_ = bf2f((F)[j]);                                          \
            acc[0][j] += v_ * s0_;                                            \
            acc[1][j] += v_ * s1_;                                            \
            acc[2][j] += v_ * s2_;                                            \
            acc[3][j] += v_ * s3_;                                            \
        }                                                                     \
    }

// ---- work: bin(256-node buckets) | weights | gstart | gsum-zero | x conv ----
__global__ __launch_bounds__(256) void work_kernel(
    const int* __restrict__ src, const int* __restrict__ dst,
    const int* __restrict__ et, int E,
    int* __restrict__ cur, int* __restrict__ tmp,
    const float* __restrict__ basis1, const float* __restrict__ comp1, const float* __restrict__ root1,
    const float* __restrict__ basis2, const float* __restrict__ comp2, const float* __restrict__ root2,
    short* __restrict__ W1t, short* __restrict__ W2t,
    const int* __restrict__ batch, int* __restrict__ gstart, int N, int G,
    const float* __restrict__ x, short* __restrict__ Xb,
    float* __restrict__ gsum,
    int ebl, int wbl, int nb, int gzb) {
    __shared__ int ss[256];
    __shared__ int lscan[257];
    __shared__ int lbase[256];
    __shared__ int lc2[256];
    __shared__ int sbuf[EPB];
    const int bid = blockIdx.x;
    const int t = threadIdx.x;

    if (bid < ebl) {  // ---- bin: LDS-staged bucket scatter into CAP regions ----
        const int e0 = bid * EPB;
        const int e1 = min(e0 + EPB, E);
        ss[t] = 0;
        __syncthreads();
        for (int e = e0 + t; e < e1; e += 256) atomicAdd(&ss[dst[e] >> 8], 1);
        __syncthreads();
        int v = ss[t];
        __syncthreads();
#pragma unroll
        for (int off = 1; off < 256; off <<= 1) {
            int u = (t >= off) ? ss[t - off] : 0;
            __syncthreads();
            ss[t] += u;
            __syncthreads();
        }
        lscan[t] = ss[t] - v;
        if (t == 255) lscan[256] = ss[255];
        lbase[t] = v ? t * CAP + atomicAdd(&cur[t], v) : 0;  // reserve
        lc2[t] = 0;
        __syncthreads();
        for (int e = e0 + t; e < e1; e += 256) {
            int d = dst[e];
            int b = d >> 8;
            int p = (src[e] << 10) | (et[e] << 8) | (d & 255);
            int pos = lscan[b] + atomicAdd(&lc2[b], 1);
            sbuf[pos] = p;
        }
        __syncthreads();
        int tot = lscan[256];
        for (int i = t; i < tot; i += 256) {
            int lo = 0, hi = 255;
            while (lo < hi) { int mid = (lo + hi + 1) >> 1; if (lscan[mid] <= i) lo = mid; else hi = mid - 1; }
            int idx = lbase[lo] + (i - lscan[lo]);
            if (idx - lo * CAP < CAP) tmp[idx] = sbuf[i];  // overflow shield
        }
    } else if (bid < ebl + wbl) {  // ---- weights: Wt[c*320+k] = Wstack[k][c] ----
        int w = (bid - ebl) * 256 + t;
        int layer = w / LWN;
        int rem = w - layer * LWN;
        int c = rem / KK;
        int k = rem - c * KK;
        const float* basis = layer ? basis2 : basis1;
        const float* comp  = layer ? comp2  : comp1;
        const float* root  = layer ? root2  : root1;
        short* Wt          = layer ? W2t    : W1t;
        float v;
        if (k < HH) {
            v = root[k * HH + c];
        } else {
            int r = (k >> 6) - 1, kk = k & 63;
            v = 0.f;
#pragma unroll
            for (int b = 0; b < RR; ++b) v += comp[r * RR + b] * basis[(b * HH + kk) * HH + c];
        }
        Wt[c * KK + k] = f2bf(v);
    } else if (bid < ebl + wbl + nb) {  // ---- gstart ----
        int i = (bid - ebl - wbl) * 256 + t;
        if (i < N) {
            int b1 = batch[i];
            int b0 = (i == 0) ? -1 : batch[i - 1];
            for (int g = b0 + 1; g <= b1; ++g) gstart[g] = i;
            if (i == N - 1)
                for (int g = b1 + 1; g <= G; ++g) gstart[g] = N;
        }
    } else if (bid < ebl + wbl + nb + gzb) {  // ---- zero gsum (float4) ----
        int i4 = (bid - ebl - wbl - nb) * 256 + t;
        if (i4 < G * (HH / 4))
            *(float4*)&gsum[i4 * 4] = make_float4(0.f, 0.f, 0.f, 0.f);
    } else {  // ---- convert x fp32 -> bf16 ----
        int i4 = (bid - ebl - wbl - nb - gzb) * 256 + t;
        int base = i4 * 4;
        if (base < N * 64) {
            float4 f = *(const float4*)&x[base];
            short4 s;
            s.x = f2bf(f.x); s.y = f2bf(f.y); s.z = f2bf(f.z); s.w = f2bf(f.w);
            *(short4*)&Xb[base] = s;
        }
    }
}

// ---- layer_build (L1, 256 thr / 32 nodes, XCD-swizzled chunks): Phase A CSR
//      from tmp bucket -> persist rp4/kend/eidxg; Phase B = FROZEN gather. ----
__global__ __launch_bounds__(256) void layer_build_kernel(
    const int* __restrict__ curg,
    const int* __restrict__ tmp,
    const short* __restrict__ Xb,
    const short* __restrict__ Wt,
    const float* __restrict__ bias,
    short* __restrict__ out, int n,
    int4* __restrict__ rp4g, int* __restrict__ kendg,
    int* __restrict__ eidxg) {
    __shared__ short xpack[2][64][32];  // 8KB
    __shared__ int cnt[128];
    __shared__ int off[129];
    __shared__ int curs[128];
    __shared__ int elist[VCAP];         // 4KB
    const int t = threadIdx.x;
    const int wv = t >> 6;
    const int pair = wv >> 1;
    const int ws = wv & 1;
    const int l = t & 63;
    const int m = l & 15;
    const int quad = l >> 4;

    // ---- XCD-aware bijective swizzle (m204): consecutive chunks -> same XCD
    // so the 8 blocks sharing a 256-node bucket fill ONE L2, not 8. ----
    const int nwg = (int)gridDim.x;
    const int orig = blockIdx.x;
    const int q = nwg >> 3, r = nwg & 7;
    const int xcd = orig & 7, idx = orig >> 3;
    const int chunk = (xcd < r ? xcd * (q + 1) : r * (q + 1) + (xcd - r) * q) + idx;

    const int node0 = chunk * 32;
    const int node = node0 + pair * 16 + m;
    const bool valid = node < n;

    // ---- Phase A ----
    const int b = node0 >> 8;
    const int dl0 = node0 & 255;
    const int tb = b * CAP;
    const int len = min(curg[b], CAP);

    for (int i = t; i < 128; i += 256) cnt[i] = 0;
    __syncthreads();
    for (int i = t; i < len; i += 256) {
        int e = tmp[tb + i];
        int w = (e & 255) - dl0;
        if ((unsigned)w < 32u) atomicAdd(&cnt[(w << 2) | ((e >> 8) & 3)], 1);
    }
    __syncthreads();
    if (t < 128) off[t] = cnt[t];
    __syncthreads();
#pragma unroll
    for (int o = 1; o < 128; o <<= 1) {
        int u = (t < 128 && t >= o) ? off[t - o] : 0;
        __syncthreads();
        if (t < 128) off[t] += u;
        __syncthreads();
    }
    if (t < 128) {
        int ex = off[t] - cnt[t];
        off[t] = ex;
        curs[t] = ex;
        if (t == 127) off[128] = ex + cnt[127];
    }
    __syncthreads();
    for (int i = t; i < len; i += 256) {
        int e = tmp[tb + i];
        int w = (e & 255) - dl0;
        if ((unsigned)w < 32u) {
            int pos = atomicAdd(&curs[(w << 2) | ((e >> 8) & 3)], 1);
            if (pos < VCAP) elist[pos] = ((e >> 10) << 2) | ((e >> 8) & 3);
        }
    }
    __syncthreads();

    // ---- persist CSR (overlaps with Phase B issue) ----
    const int eb = chunk * VCAP;
    if (t < 32 && node0 + t < n) {
        int c4 = t << 2;
        rp4g[node0 + t] = make_int4(eb + min(off[c4], VCAP), eb + min(off[c4 + 1], VCAP),
                                    eb + min(off[c4 + 2], VCAP), eb + min(off[c4 + 3], VCAP));
        kendg[node0 + t] = eb + min(off[c4 + 4], VCAP);
    }
    {
        int fill = min(off[128], VCAP);
        for (int i = t; i < fill; i += 256) eidxg[eb + i] = elist[i];
    }

    // ---- Phase B: FROZEN gather from LDS elist ----
    float acc[4][8];
#pragma unroll
    for (int r2 = 0; r2 < 4; ++r2)
#pragma unroll
        for (int j = 0; j < 8; ++j) acc[r2][j] = 0.f;

    const int w4 = ((pair << 4) | m) << 2;
    const int k0 = min(off[w4], VCAP);
    const int k1 = min(off[w4 + 4], VCAP);
    float4 iv;
    iv.x = 1.0f / fmaxf((float)cnt[w4 + 0], 1.0f);
    iv.y = 1.0f / fmaxf((float)cnt[w4 + 1], 1.0f);
    iv.z = 1.0f / fmaxf((float)cnt[w4 + 2], 1.0f);
    iv.w = 1.0f / fmaxf((float)cnt[w4 + 3], 1.0f);
    const short* xbq = Xb + ws * 32 + quad * 8;

    int k = k0;
    for (; k + 3 < k1; k += 4) {
        int p0 = elist[k];
        int p1 = elist[k + 1];
        int p2 = elist[k + 2];
        int p3 = elist[k + 3];
        const short* a0p = xbq + (size_t)(p0 >> 2) * 64;
        const short* a1p = xbq + (size_t)(p1 >> 2) * 64;
        const short* a2p = xbq + (size_t)(p2 >> 2) * 64;
        const short* a3p = xbq + (size_t)(p3 >> 2) * 64;
        frag_ab f0 = *(const frag_ab*)a0p;
        frag_ab f1 = *(const frag_ab*)a1p;
        frag_ab f2 = *(const frag_ab*)a2p;
        frag_ab f3 = *(const frag_ab*)a3p;
        ACCM(p0, f0)
        ACCM(p1, f1)
        ACCM(p2, f2)
        ACCM(p3, f3)
    }
    for (; k < k1; ++k) {
        int p0 = elist[k];
        const short* a0p = xbq + (size_t)(p0 >> 2) * 64;
        frag_ab f0 = *(const frag_ab*)a0p;
        ACCM(p0, f0)
    }

    frag_ab y[4];
    {
        float s0 = iv.x, s1 = iv.y, s2 = iv.z, s3 = iv.w;
#pragma unroll
        for (int j = 0; j < 8; ++j) {
            y[0][j] = f2bf(acc[0][j] * s0);
            y[1][j] = f2bf(acc[1][j] * s1);
            y[2][j] = f2bf(acc[2][j] * s2);
            y[3][j] = f2bf(acc[3][j] * s3);
        }
    }

    if (ws == 1) {
#pragma unroll
        for (int r2 = 0; r2 < 4; ++r2)
            *(frag_ab*)&xpack[pair][l][r2 * 8] = y[r2];
    }
    __syncthreads();
    if (ws == 1) return;

    frag_ab a[10];
    a[0] = frag_ab{};
    a[1] = frag_ab{};
    if (valid) {
        const short* xr = Xb + (size_t)node * 64 + quad * 8;
        a[0] = *(const frag_ab*)xr;
        a[1] = *(const frag_ab*)(xr + 32);
    }
#pragma unroll
    for (int r2 = 0; r2 < 4; ++r2) {
        a[2 + 2 * r2] = y[r2];
        a[3 + 2 * r2] = *(const frag_ab*)&xpack[pair][l][r2 * 8];
    }

    const int nrow_base = node0 + pair * 16 + quad * 4;
#pragma unroll
    for (int ct = 0; ct < 4; ++ct) {
        const short* bp = Wt + (size_t)(ct * 16 + m) * KK + quad * 8;
        frag_cd c = {0.f, 0.f, 0.f, 0.f};
#pragma unroll
        for (int f = 0; f < 10; ++f) {
            frag_ab bf = *(const frag_ab*)(bp + f * 32);
            c = __builtin_amdgcn_mfma_f32_16x16x32_bf16(a[f], bf, c, 0, 0, 0);
        }
        int col = ct * 16 + m;
        float bv = bias[col];
#pragma unroll
        for (int r2 = 0; r2 < 4; ++r2) {
            int nr = nrow_base + r2;
            if (nr < n) out[(size_t)nr * 64 + col] = f2bf(fmaxf(c[r2] + bv, 0.f));
        }
    }
}

// ---- layer_read (L2, 256 thr / 32 nodes): gather from persisted CSR +
//      LDS-first pooling -> gsum. ----
__global__ __launch_bounds__(256) void layer_read_kernel(
    const int4* __restrict__ rp4g, const int* __restrict__ kendg,
    const int* __restrict__ eidxg,
    const short* __restrict__ Xb,
    const short* __restrict__ Wt,
    const float* __restrict__ bias,
    int n, const int* __restrict__ batch, float* __restrict__ gsum) {
    __shared__ short xpack[2][64][32];  // 8KB
    __shared__ float pgs[NSLOT * 64];   // 2KB
    const int t = threadIdx.x;
    const int wv = t >> 6;
    const int pair = wv >> 1;
    const int ws = wv & 1;
    const int l = t & 63;
    const int m = l & 15;
    const int quad = l >> 4;
    const int node0 = blockIdx.x * 32;
    const int node = node0 + pair * 16 + m;
    const bool valid = node < n;

    for (int i = t; i < NSLOT * 64; i += 256) pgs[i] = 0.f;

    float acc[4][8];
#pragma unroll
    for (int r = 0; r < 4; ++r)
#pragma unroll
        for (int j = 0; j < 8; ++j) acc[r][j] = 0.f;

    int k0 = 0, k1 = 0;
    float4 iv = make_float4(0.f, 0.f, 0.f, 0.f);
    if (valid) {
        int4 r4 = rp4g[node];
        int kend = kendg[node];
        k0 = r4.x;
        k1 = kend;
        iv.x = 1.0f / fmaxf((float)(r4.y - r4.x), 1.0f);
        iv.y = 1.0f / fmaxf((float)(r4.z - r4.y), 1.0f);
        iv.z = 1.0f / fmaxf((float)(r4.w - r4.z), 1.0f);
        iv.w = 1.0f / fmaxf((float)(kend - r4.w), 1.0f);
    }
    const short* xbq = Xb + ws * 32 + quad * 8;

    int k = k0;
    for (; k + 3 < k1; k += 4) {  // FROZEN 4-deep
        int p0 = eidxg[k];
        int p1 = eidxg[k + 1];
        int p2 = eidxg[k + 2];
        int p3 = eidxg[k + 3];
        const short* a0p = xbq + (size_t)(p0 >> 2) * 64;
        const short* a1p = xbq + (size_t)(p1 >> 2) * 64;
        const short* a2p = xbq + (size_t)(p2 >> 2) * 64;
        const short* a3p = xbq + (size_t)(p3 >> 2) * 64;
        frag_ab f0 = *(const frag_ab*)a0p;
        frag_ab f1 = *(const frag_ab*)a1p;
        frag_ab f2 = *(const frag_ab*)a2p;
        frag_ab f3 = *(const frag_ab*)a3p;
        ACCM(p0, f0)
        ACCM(p1, f1)
        ACCM(p2, f2)
        ACCM(p3, f3)
    }
    for (; k < k1; ++k) {
        int p0 = eidxg[k];
        const short* a0p = xbq + (size_t)(p0 >> 2) * 64;
        frag_ab f0 = *(const frag_ab*)a0p;
        ACCM(p0, f0)
    }

    frag_ab y[4];
    {
        float s0 = iv.x, s1 = iv.y, s2 = iv.z, s3 = iv.w;
#pragma unroll
        for (int j = 0; j < 8; ++j) {
            y[0][j] = f2bf(acc[0][j] * s0);
            y[1][j] = f2bf(acc[1][j] * s1);
            y[2][j] = f2bf(acc[2][j] * s2);
            y[3][j] = f2bf(acc[3][j] * s3);
        }
    }

    if (ws == 1) {
#pragma unroll
        for (int r = 0; r < 4; ++r)
            *(frag_ab*)&xpack[pair][l][r * 8] = y[r];
    }
    __syncthreads();

    const int nrow_base = node0 + pair * 16 + quad * 4;
    const int batch_base = batch[node0];

    if (ws == 0) {
        frag_ab a[10];
        a[0] = frag_ab{};
        a[1] = frag_ab{};
        if (valid) {
            const short* xr = Xb + (size_t)node * 64 + quad * 8;
            a[0] = *(const frag_ab*)xr;
            a[1] = *(const frag_ab*)(xr + 32);
        }
#pragma unroll
        for (int r = 0; r < 4; ++r) {
            a[2 + 2 * r] = y[r];
            a[3 + 2 * r] = *(const frag_ab*)&xpack[pair][l][r * 8];
        }

        int bv4[4];
        if (nrow_base + 3 < n) {
            int4 bb = *(const int4*)&batch[nrow_base];
            bv4[0] = bb.x; bv4[1] = bb.y; bv4[2] = bb.z; bv4[3] = bb.w;
        } else {
#pragma unroll
            for (int r = 0; r < 4; ++r)
                bv4[r] = (nrow_base + r < n) ? batch[nrow_base + r] : 0;
        }

#pragma unroll
        for (int ct = 0; ct < 4; ++ct) {
            const short* bp = Wt + (size_t)(ct * 16 + m) * KK + quad * 8;
            frag_cd c = {0.f, 0.f, 0.f, 0.f};
#pragma unroll
            for (int f = 0; f < 10; ++f) {
                frag_ab bf = *(const frag_ab*)(bp + f * 32);
                c = __builtin_amdgcn_mfma_f32_16x16x32_bf16(a[f], bf, c, 0, 0, 0);
            }
            int col = ct * 16 + m;
            float bv = bias[col];
#pragma unroll
            for (int r = 0; r < 4; ++r) {
                int nr = nrow_base + r;
                if (nr < n) {
                    float v = fmaxf(c[r] + bv, 0.f);
                    int g = bv4[r] - batch_base;
                    if (g < NSLOT)
                        atomicAdd(&pgs[g * 64 + col], v);
                    else
                        atomicAdd(&gsum[(size_t)bv4[r] * 64 + col], v);
                }
            }
        }
    }

    __syncthreads();
    int node_last = min(node0 + 31, n - 1);
    int gspan = batch[node_last] - batch_base;
    for (int i = t; i < NSLOT * 64; i += 256) {
        int s = i >> 6;
        if (s <= gspan) {
            float v = pgs[i];
            if (v != 0.f) atomicAdd(&gsum[(size_t)(batch_base + s) * 64 + (i & 63)], v);
        }
    }
}

// ---- cls: mean + linear from gsum (normal loads; kernel boundary = coherence) ----
__global__ __launch_bounds__(256) void cls_kernel(const float* __restrict__ gsum,
                                                  const int* __restrict__ gstart,
                                                  const float* __restrict__ w,
                                                  const float* __restrict__ bcls,
                                                  float* __restrict__ out, int G) {
    const int g = blockIdx.x * 256 + threadIdx.x;
    if (g >= G) return;
    int s = gstart[g], e = gstart[g + 1];
    float invc = 1.0f / fmaxf((float)(e - s), 1.0f);
    float o0 = 0.f, o1 = 0.f, o2 = 0.f, o3 = 0.f;
    const float* gr = gsum + (size_t)g * 64;
#pragma unroll 8
    for (int hh = 0; hh < 64; ++hh) {
        float mm = gr[hh] * invc;
        float4 wr = *(const float4*)&w[hh * 4];
        o0 += mm * wr.x;
        o1 += mm * wr.y;
        o2 += mm * wr.z;
        o3 += mm * wr.w;
    }
    float4 o = make_float4(o0 + bcls[0], o1 + bcls[1], o2 + bcls[2], o3 + bcls[3]);
    *(float4*)&out[g * 4] = o;
}

extern "C" void kernel_launch(void* const* d_in, const int* in_sizes, int n_in,
                              void* d_out, int out_size, void* d_ws, size_t ws_size,
                              hipStream_t stream) {
    const float* x        = (const float*)d_in[0];
    const int* edge_index = (const int*)d_in[1];
    const int* edge_type  = (const int*)d_in[2];
    const int* batch      = (const int*)d_in[3];
    const float* basis1 = (const float*)d_in[4];
    const float* comp1  = (const float*)d_in[5];
    const float* root1  = (const float*)d_in[6];
    const float* bias1  = (const float*)d_in[7];
    const float* basis2 = (const float*)d_in[8];
    const float* comp2  = (const float*)d_in[9];
    const float* root2  = (const float*)d_in[10];
    const float* bias2  = (const float*)d_in[11];
    const float* clas_w = (const float*)d_in[12];
    const float* clas_b = (const float*)d_in[13];

    const int N = in_sizes[0] / 64;
    const int E = in_sizes[2];
    const int G = out_size / 4;
    const int* src = edge_index;
    const int* dst = edge_index + E;
    const int nbuck = (N + 255) >> 8;
    const int build_blocks = (N + 31) / 32;
    const int read_blocks  = (N + 31) / 32;

    char* base = (char*)d_ws;
    size_t off = 0;
    auto carve = [&](size_t bytes) { void* p = base + off; off = (off + bytes + 15) & ~(size_t)15; return p; };
    int*   cur     = (int*)carve(sizeof(int) * 256);
    float* gsum    = (float*)carve(sizeof(float) * (size_t)G * HH);
    int*   gstart  = (int*)carve(sizeof(int) * ((size_t)G + 1));
    int*   tmp     = (int*)carve(sizeof(int) * (size_t)nbuck * CAP);
    int4*  rp4g    = (int4*)carve(sizeof(int4) * (size_t)N);
    int*   kendg   = (int*)carve(sizeof(int) * (size_t)N);
    int*   eidxg   = (int*)carve(sizeof(int) * (size_t)build_blocks * VCAP);
    short* W1t     = (short*)carve(sizeof(short) * LWN);
    short* W2t     = (short*)carve(sizeof(short) * LWN);
    short* Xb1     = (short*)carve(sizeof(short) * (size_t)N * 64);
    short* H1      = (short*)carve(sizeof(short) * (size_t)N * 64);
    float* gout    = (float*)d_out;

    const int ebl = (E + EPB - 1) / EPB;
    const int wbl = (2 * LWN + 255) / 256;
    const int nb  = (N + 255) / 256;
    const int gzb = (G * (HH / 4) + 255) / 256;
    const int cvb = (N * 64 / 4 + 255) / 256;
    const int work_blocks = ebl + wbl + nb + gzb + cvb;

    hipMemsetAsync(cur, 0, sizeof(int) * 256, stream);

    work_kernel<<<work_blocks, 256, 0, stream>>>(
        src, dst, edge_type, E, cur, tmp,
        basis1, comp1, root1, basis2, comp2, root2, W1t, W2t,
        batch, gstart, N, G, x, Xb1, gsum, ebl, wbl, nb, gzb);

    layer_build_kernel<<<build_blocks, 256, 0, stream>>>(
        cur, tmp, Xb1, W1t, bias1, H1, N, rp4g, kendg, eidxg);
    layer_read_kernel<<<read_blocks, 256, 0, stream>>>(
        rp4g, kendg, eidxg, H1, W2t, bias2, N, batch, gsum);

    cls_kernel<<<(G + 255) / 256, 256, 0, stream>>>(
        gsum, gstart, clas_w, clas_b, gout, G);
}

// Round 14
// 209.352 us; speedup vs baseline: 1.0979x; 1.0478x over previous
//
#include <hip/hip_runtime.h>

// H2G2: 2-layer RGCN (R=4, per-relation mean) + mean-pool + linear.
// R10 (231us, layer 47): register-resident fused layer. R11 FAILED: VGPR cap
//   -> scratch spill. R12 (229.6): channel-split wave pair; layer pinned 47.0.
// R13 FAILED: random 4B global writes = line RMW. R14 FAILED: grid.sync
//   ~80-90us each w/ idle grid. R15: CAP-bucket OK; per-element device
//   atomics FAILED. R16 (219.6): 6-dispatch pipeline, layers 47.0.
// R17 FAILED: 8-edge unroll -> occ crash. MLP model: layer ~ 1/(waves x
//   depth) until ~96 lines/CU, then per-XCD random-fill-rate floor ~0.9
//   lines/cy (R21 null proves rate-bound). Gather FROZEN. FETCH 52MB compuls.
// R18 (275): LDS-first pooling OK; 1-block uncached cls = 70us serial tail.
// R19 (232.4): in-layer CSR paid twice. R20 (218.3, BEST): CSR once in
//   build, persisted. R22 (229.9): fine bins fixed build fill but broke bin
//   write coalescing (runs of 2.6 x 4B = 6x write amp). REVERTED.
// R23 (219.4): XCD swizzle removed build over-fetch (FETCH 63.5->49.2MB)
//   but only -2.4us -> Phase A is BARRIER/LATENCY-bound (16-barrier LDS
//   scans + serial passes at 2-3 blocks/CU), not fill-bound.
// R24: cut barrier/serial overhead. bin: shfl_up wave-scan (20->5 barriers)
//   + sbkt[] tag replaces 8-step binary search copy-out. build Phase A:
//   shuffle 128-scan (16->3 barriers). Keep swizzle + frozen structure.
//   DECISION RULE: if total >= 214 (within 2% of 218.3), declare roofline.

#define RR 4
#define HH 64
#define KK 320         // (RR+1)*HH
#define LWN (HH * KK)  // weights per layer = 20480
#define EPB 2048       // edges per bin chunk
#define CAP 6144       // per-256-node-bucket capacity (mean 4096, +32 sigma)
#define NSLOT 8        // LDS pool slots
#define VCAP 1024      // per-build-block edge list cap (mean 512, +22 sigma)

using frag_ab = __attribute__((ext_vector_type(8))) short;
using frag_cd = __attribute__((ext_vector_type(4))) float;

__device__ inline short f2bf(float f) {
    unsigned u = __builtin_bit_cast(unsigned, f);
    unsigned r = u + 0x7fffu + ((u >> 16) & 1u);  // RNE
    return (short)(r >> 16);
}
__device__ inline float bf2f(short s) {
    unsigned u = ((unsigned)(unsigned short)s) << 16;
    return __builtin_bit_cast(float, u);
}

// ---- shared gather accumulate macro ----
#define ACCM(P, F)                                                            \
    {                                                                         \
        int r_ = (P) & 3;                                                     \
        float s0_ = (r_ == 0) ? 1.f : 0.f;                                    \
        float s1_ = (r_ == 1) ? 1.f : 0.f;                                    \
        float s2_ = (r_ == 2) ? 1.f : 0.f;                                    \
        float s3_ = (r_ == 3) ? 1.f : 0.f;                                    \
        _Pragma("unroll") for (int j = 0; j < 8; ++j) {                       \
            float v_ = bf2f((F)[j]);                                          \
            acc[0][j] += v_ * s0_;                                            \
            acc[1][j] += v_ * s1_;                                            \
            acc[2][j] += v_ * s2_;                                            \
            acc[3][j] += v_ * s3_;                                            \
        }                                                                     \
    }

// ---- work: bin(shuffle-scan) | weights | gstart | gsum-zero | x conv ----
__global__ __launch_bounds__(256) void work_kernel(
    const int* __restrict__ src, const int* __restrict__ dst,
    const int* __restrict__ et, int E,
    int* __restrict__ cur, int* __restrict__ tmp,
    const float* __restrict__ basis1, const float* __restrict__ comp1, const float* __restrict__ root1,
    const float* __restrict__ basis2, const float* __restrict__ comp2, const float* __restrict__ root2,
    short* __restrict__ W1t, short* __restrict__ W2t,
    const int* __restrict__ batch, int* __restrict__ gstart, int N, int G,
    const float* __restrict__ x, short* __restrict__ Xb,
    float* __restrict__ gsum,
    int ebl, int wbl, int nb, int gzb) {
    __shared__ int hist[256];
    __shared__ int lscan[256];
    __shared__ int lbase[256];
    __shared__ int lc2[256];
    __shared__ int wsum[4];
    __shared__ int sbuf[EPB];
    __shared__ unsigned char sbkt[EPB];
    const int bid = blockIdx.x;
    const int t = threadIdx.x;

    if (bid < ebl) {  // ---- bin: LDS-staged bucket scatter into CAP regions ----
        const int e0 = bid * EPB;
        const int e1 = min(e0 + EPB, E);
        hist[t] = 0;
        __syncthreads();
        for (int e = e0 + t; e < e1; e += 256) atomicAdd(&hist[dst[e] >> 8], 1);
        __syncthreads();
        int v = hist[t];
        // shuffle inclusive scan over 256 threads (4 waves)
        const int lane = t & 63, w = t >> 6;
        int sv = v;
#pragma unroll
        for (int off = 1; off < 64; off <<= 1) {
            int u = __shfl_up(sv, off, 64);
            if (lane >= off) sv += u;
        }
        if (lane == 63) wsum[w] = sv;
        __syncthreads();
        int wpre = 0;
#pragma unroll
        for (int i = 0; i < 4; ++i) wpre += (i < w) ? wsum[i] : 0;
        sv += wpre;                 // inclusive
        lscan[t] = sv - v;          // exclusive
        lbase[t] = v ? t * CAP + atomicAdd(&cur[t], v) : 0;  // reserve
        lc2[t] = 0;
        __syncthreads();
        for (int e = e0 + t; e < e1; e += 256) {
            int d = dst[e];
            int b = d >> 8;
            int p = (src[e] << 10) | (et[e] << 8) | (d & 255);
            int pos = lscan[b] + atomicAdd(&lc2[b], 1);
            sbuf[pos] = p;
            sbkt[pos] = (unsigned char)b;
        }
        __syncthreads();
        int tot = e1 - e0;
        for (int i = t; i < tot; i += 256) {
            int b = sbkt[i];
            int idx = lbase[b] + (i - lscan[b]);
            if (idx - b * CAP < CAP) tmp[idx] = sbuf[i];  // overflow shield
        }
    } else if (bid < ebl + wbl) {  // ---- weights: Wt[c*320+k] = Wstack[k][c] ----
        int w = (bid - ebl) * 256 + t;
        int layer = w / LWN;
        int rem = w - layer * LWN;
        int c = rem / KK;
        int k = rem - c * KK;
        const float* basis = layer ? basis2 : basis1;
        const float* comp  = layer ? comp2  : comp1;
        const float* root  = layer ? root2  : root1;
        short* Wt          = layer ? W2t    : W1t;
        float v;
        if (k < HH) {
            v = root[k * HH + c];
        } else {
            int r = (k >> 6) - 1, kk = k & 63;
            v = 0.f;
#pragma unroll
            for (int b = 0; b < RR; ++b) v += comp[r * RR + b] * basis[(b * HH + kk) * HH + c];
        }
        Wt[c * KK + k] = f2bf(v);
    } else if (bid < ebl + wbl + nb) {  // ---- gstart ----
        int i = (bid - ebl - wbl) * 256 + t;
        if (i < N) {
            int b1 = batch[i];
            int b0 = (i == 0) ? -1 : batch[i - 1];
            for (int g = b0 + 1; g <= b1; ++g) gstart[g] = i;
            if (i == N - 1)
                for (int g = b1 + 1; g <= G; ++g) gstart[g] = N;
        }
    } else if (bid < ebl + wbl + nb + gzb) {  // ---- zero gsum (float4) ----
        int i4 = (bid - ebl - wbl - nb) * 256 + t;
        if (i4 < G * (HH / 4))
            *(float4*)&gsum[i4 * 4] = make_float4(0.f, 0.f, 0.f, 0.f);
    } else {  // ---- convert x fp32 -> bf16 ----
        int i4 = (bid - ebl - wbl - nb - gzb) * 256 + t;
        int base = i4 * 4;
        if (base < N * 64) {
            float4 f = *(const float4*)&x[base];
            short4 s;
            s.x = f2bf(f.x); s.y = f2bf(f.y); s.z = f2bf(f.z); s.w = f2bf(f.w);
            *(short4*)&Xb[base] = s;
        }
    }
}

// ---- layer_build (L1, 256 thr / 32 nodes, XCD-swizzled): Phase A CSR
//      (shuffle scan) -> persist rp4/kend/eidxg; Phase B = FROZEN gather. ----
__global__ __launch_bounds__(256) void layer_build_kernel(
    const int* __restrict__ curg,
    const int* __restrict__ tmp,
    const short* __restrict__ Xb,
    const short* __restrict__ Wt,
    const float* __restrict__ bias,
    short* __restrict__ out, int n,
    int4* __restrict__ rp4g, int* __restrict__ kendg,
    int* __restrict__ eidxg) {
    __shared__ short xpack[2][64][32];  // 8KB
    __shared__ int cnt[128];
    __shared__ int off[129];
    __shared__ int curs[128];
    __shared__ int wsumA[2];
    __shared__ int elist[VCAP];         // 4KB
    const int t = threadIdx.x;
    const int wv = t >> 6;
    const int pair = wv >> 1;
    const int ws = wv & 1;
    const int l = t & 63;
    const int m = l & 15;
    const int quad = l >> 4;

    // ---- XCD-aware bijective swizzle (m204): bucket's 8 blocks -> one XCD ----
    const int nwg = (int)gridDim.x;
    const int orig = blockIdx.x;
    const int q = nwg >> 3, r = nwg & 7;
    const int xcd = orig & 7, idx = orig >> 3;
    const int chunk = (xcd < r ? xcd * (q + 1) : r * (q + 1) + (xcd - r) * q) + idx;

    const int node0 = chunk * 32;
    const int node = node0 + pair * 16 + m;
    const bool valid = node < n;

    // ---- Phase A ----
    const int b = node0 >> 8;
    const int dl0 = node0 & 255;
    const int tb = b * CAP;
    const int len = min(curg[b], CAP);

    for (int i = t; i < 128; i += 256) cnt[i] = 0;
    __syncthreads();
    for (int i = t; i < len; i += 256) {
        int e = tmp[tb + i];
        int w = (e & 255) - dl0;
        if ((unsigned)w < 32u) atomicAdd(&cnt[(w << 2) | ((e >> 8) & 3)], 1);
    }
    __syncthreads();
    // shuffle scan of cnt[0..127] (2 waves)
    {
        int v128 = (t < 128) ? cnt[t] : 0;
        int sv = v128;
#pragma unroll
        for (int o = 1; o < 64; o <<= 1) {
            int u = __shfl_up(sv, o, 64);
            if (l >= o) sv += u;
        }
        if (t == 63) wsumA[0] = sv;
        if (t == 127) wsumA[1] = sv;
        __syncthreads();
        if (t < 128) {
            int incl = sv + ((t >= 64) ? wsumA[0] : 0);
            int ex = incl - v128;
            off[t] = ex;
            curs[t] = ex;
            if (t == 127) off[128] = incl;
        }
        __syncthreads();
    }
    for (int i = t; i < len; i += 256) {
        int e = tmp[tb + i];
        int w = (e & 255) - dl0;
        if ((unsigned)w < 32u) {
            int pos = atomicAdd(&curs[(w << 2) | ((e >> 8) & 3)], 1);
            if (pos < VCAP) elist[pos] = ((e >> 10) << 2) | ((e >> 8) & 3);
        }
    }
    __syncthreads();

    // ---- persist CSR (overlaps with Phase B issue) ----
    const int eb = chunk * VCAP;
    if (t < 32 && node0 + t < n) {
        int c4 = t << 2;
        rp4g[node0 + t] = make_int4(eb + min(off[c4], VCAP), eb + min(off[c4 + 1], VCAP),
                                    eb + min(off[c4 + 2], VCAP), eb + min(off[c4 + 3], VCAP));
        kendg[node0 + t] = eb + min(off[c4 + 4], VCAP);
    }
    {
        int fill = min(off[128], VCAP);
        for (int i = t; i < fill; i += 256) eidxg[eb + i] = elist[i];
    }

    // ---- Phase B: FROZEN gather from LDS elist ----
    float acc[4][8];
#pragma unroll
    for (int r2 = 0; r2 < 4; ++r2)
#pragma unroll
        for (int j = 0; j < 8; ++j) acc[r2][j] = 0.f;

    const int w4 = ((pair << 4) | m) << 2;
    const int k0 = min(off[w4], VCAP);
    const int k1 = min(off[w4 + 4], VCAP);
    float4 iv;
    iv.x = 1.0f / fmaxf((float)cnt[w4 + 0], 1.0f);
    iv.y = 1.0f / fmaxf((float)cnt[w4 + 1], 1.0f);
    iv.z = 1.0f / fmaxf((float)cnt[w4 + 2], 1.0f);
    iv.w = 1.0f / fmaxf((float)cnt[w4 + 3], 1.0f);
    const short* xbq = Xb + ws * 32 + quad * 8;

    int k = k0;
    for (; k + 3 < k1; k += 4) {
        int p0 = elist[k];
        int p1 = elist[k + 1];
        int p2 = elist[k + 2];
        int p3 = elist[k + 3];
        const short* a0p = xbq + (size_t)(p0 >> 2) * 64;
        const short* a1p = xbq + (size_t)(p1 >> 2) * 64;
        const short* a2p = xbq + (size_t)(p2 >> 2) * 64;
        const short* a3p = xbq + (size_t)(p3 >> 2) * 64;
        frag_ab f0 = *(const frag_ab*)a0p;
        frag_ab f1 = *(const frag_ab*)a1p;
        frag_ab f2 = *(const frag_ab*)a2p;
        frag_ab f3 = *(const frag_ab*)a3p;
        ACCM(p0, f0)
        ACCM(p1, f1)
        ACCM(p2, f2)
        ACCM(p3, f3)
    }
    for (; k < k1; ++k) {
        int p0 = elist[k];
        const short* a0p = xbq + (size_t)(p0 >> 2) * 64;
        frag_ab f0 = *(const frag_ab*)a0p;
        ACCM(p0, f0)
    }

    frag_ab y[4];
    {
        float s0 = iv.x, s1 = iv.y, s2 = iv.z, s3 = iv.w;
#pragma unroll
        for (int j = 0; j < 8; ++j) {
            y[0][j] = f2bf(acc[0][j] * s0);
            y[1][j] = f2bf(acc[1][j] * s1);
            y[2][j] = f2bf(acc[2][j] * s2);
            y[3][j] = f2bf(acc[3][j] * s3);
        }
    }

    if (ws == 1) {
#pragma unroll
        for (int r2 = 0; r2 < 4; ++r2)
            *(frag_ab*)&xpack[pair][l][r2 * 8] = y[r2];
    }
    __syncthreads();
    if (ws == 1) return;

    frag_ab a[10];
    a[0] = frag_ab{};
    a[1] = frag_ab{};
    if (valid) {
        const short* xr = Xb + (size_t)node * 64 + quad * 8;
        a[0] = *(const frag_ab*)xr;
        a[1] = *(const frag_ab*)(xr + 32);
    }
#pragma unroll
    for (int r2 = 0; r2 < 4; ++r2) {
        a[2 + 2 * r2] = y[r2];
        a[3 + 2 * r2] = *(const frag_ab*)&xpack[pair][l][r2 * 8];
    }

    const int nrow_base = node0 + pair * 16 + quad * 4;
#pragma unroll
    for (int ct = 0; ct < 4; ++ct) {
        const short* bp = Wt + (size_t)(ct * 16 + m) * KK + quad * 8;
        frag_cd c = {0.f, 0.f, 0.f, 0.f};
#pragma unroll
        for (int f = 0; f < 10; ++f) {
            frag_ab bf = *(const frag_ab*)(bp + f * 32);
            c = __builtin_amdgcn_mfma_f32_16x16x32_bf16(a[f], bf, c, 0, 0, 0);
        }
        int col = ct * 16 + m;
        float bv = bias[col];
#pragma unroll
        for (int r2 = 0; r2 < 4; ++r2) {
            int nr = nrow_base + r2;
            if (nr < n) out[(size_t)nr * 64 + col] = f2bf(fmaxf(c[r2] + bv, 0.f));
        }
    }
}

// ---- layer_read (L2, 256 thr / 32 nodes): gather from persisted CSR +
//      LDS-first pooling -> gsum. ----
__global__ __launch_bounds__(256) void layer_read_kernel(
    const int4* __restrict__ rp4g, const int* __restrict__ kendg,
    const int* __restrict__ eidxg,
    const short* __restrict__ Xb,
    const short* __restrict__ Wt,
    const float* __restrict__ bias,
    int n, const int* __restrict__ batch, float* __restrict__ gsum) {
    __shared__ short xpack[2][64][32];  // 8KB
    __shared__ float pgs[NSLOT * 64];   // 2KB
    const int t = threadIdx.x;
    const int wv = t >> 6;
    const int pair = wv >> 1;
    const int ws = wv & 1;
    const int l = t & 63;
    const int m = l & 15;
    const int quad = l >> 4;
    const int node0 = blockIdx.x * 32;
    const int node = node0 + pair * 16 + m;
    const bool valid = node < n;

    for (int i = t; i < NSLOT * 64; i += 256) pgs[i] = 0.f;

    float acc[4][8];
#pragma unroll
    for (int r = 0; r < 4; ++r)
#pragma unroll
        for (int j = 0; j < 8; ++j) acc[r][j] = 0.f;

    int k0 = 0, k1 = 0;
    float4 iv = make_float4(0.f, 0.f, 0.f, 0.f);
    if (valid) {
        int4 r4 = rp4g[node];
        int kend = kendg[node];
        k0 = r4.x;
        k1 = kend;
        iv.x = 1.0f / fmaxf((float)(r4.y - r4.x), 1.0f);
        iv.y = 1.0f / fmaxf((float)(r4.z - r4.y), 1.0f);
        iv.z = 1.0f / fmaxf((float)(r4.w - r4.z), 1.0f);
        iv.w = 1.0f / fmaxf((float)(kend - r4.w), 1.0f);
    }
    const short* xbq = Xb + ws * 32 + quad * 8;

    int k = k0;
    for (; k + 3 < k1; k += 4) {  // FROZEN 4-deep
        int p0 = eidxg[k];
        int p1 = eidxg[k + 1];
        int p2 = eidxg[k + 2];
        int p3 = eidxg[k + 3];
        const short* a0p = xbq + (size_t)(p0 >> 2) * 64;
        const short* a1p = xbq + (size_t)(p1 >> 2) * 64;
        const short* a2p = xbq + (size_t)(p2 >> 2) * 64;
        const short* a3p = xbq + (size_t)(p3 >> 2) * 64;
        frag_ab f0 = *(const frag_ab*)a0p;
        frag_ab f1 = *(const frag_ab*)a1p;
        frag_ab f2 = *(const frag_ab*)a2p;
        frag_ab f3 = *(const frag_ab*)a3p;
        ACCM(p0, f0)
        ACCM(p1, f1)
        ACCM(p2, f2)
        ACCM(p3, f3)
    }
    for (; k < k1; ++k) {
        int p0 = eidxg[k];
        const short* a0p = xbq + (size_t)(p0 >> 2) * 64;
        frag_ab f0 = *(const frag_ab*)a0p;
        ACCM(p0, f0)
    }

    frag_ab y[4];
    {
        float s0 = iv.x, s1 = iv.y, s2 = iv.z, s3 = iv.w;
#pragma unroll
        for (int j = 0; j < 8; ++j) {
            y[0][j] = f2bf(acc[0][j] * s0);
            y[1][j] = f2bf(acc[1][j] * s1);
            y[2][j] = f2bf(acc[2][j] * s2);
            y[3][j] = f2bf(acc[3][j] * s3);
        }
    }

    if (ws == 1) {
#pragma unroll
        for (int r = 0; r < 4; ++r)
            *(frag_ab*)&xpack[pair][l][r * 8] = y[r];
    }
    __syncthreads();

    const int nrow_base = node0 + pair * 16 + quad * 4;
    const int batch_base = batch[node0];

    if (ws == 0) {
        frag_ab a[10];
        a[0] = frag_ab{};
        a[1] = frag_ab{};
        if (valid) {
            const short* xr = Xb + (size_t)node * 64 + quad * 8;
            a[0] = *(const frag_ab*)xr;
            a[1] = *(const frag_ab*)(xr + 32);
        }
#pragma unroll
        for (int r = 0; r < 4; ++r) {
            a[2 + 2 * r] = y[r];
            a[3 + 2 * r] = *(const frag_ab*)&xpack[pair][l][r * 8];
        }

        int bv4[4];
        if (nrow_base + 3 < n) {
            int4 bb = *(const int4*)&batch[nrow_base];
            bv4[0] = bb.x; bv4[1] = bb.y; bv4[2] = bb.z; bv4[3] = bb.w;
        } else {
#pragma unroll
            for (int r = 0; r < 4; ++r)
                bv4[r] = (nrow_base + r < n) ? batch[nrow_base + r] : 0;
        }

#pragma unroll
        for (int ct = 0; ct < 4; ++ct) {
            const short* bp = Wt + (size_t)(ct * 16 + m) * KK + quad * 8;
            frag_cd c = {0.f, 0.f, 0.f, 0.f};
#pragma unroll
            for (int f = 0; f < 10; ++f) {
                frag_ab bf = *(const frag_ab*)(bp + f * 32);
                c = __builtin_amdgcn_mfma_f32_16x16x32_bf16(a[f], bf, c, 0, 0, 0);
            }
            int col = ct * 16 + m;
            float bv = bias[col];
#pragma unroll
            for (int r = 0; r < 4; ++r) {
                int nr = nrow_base + r;
                if (nr < n) {
                    float v = fmaxf(c[r] + bv, 0.f);
                    int g = bv4[r] - batch_base;
                    if (g < NSLOT)
                        atomicAdd(&pgs[g * 64 + col], v);
                    else
                        atomicAdd(&gsum[(size_t)bv4[r] * 64 + col], v);
                }
            }
        }
    }

    __syncthreads();
    int node_last = min(node0 + 31, n - 1);
    int gspan = batch[node_last] - batch_base;
    for (int i = t; i < NSLOT * 64; i += 256) {
        int s = i >> 6;
        if (s <= gspan) {
            float v = pgs[i];
            if (v != 0.f) atomicAdd(&gsum[(size_t)(batch_base + s) * 64 + (i & 63)], v);
        }
    }
}

// ---- cls: mean + linear from gsum (normal loads; kernel boundary = coherence) ----
__global__ __launch_bounds__(256) void cls_kernel(const float* __restrict__ gsum,
                                                  const int* __restrict__ gstart,
                                                  const float* __restrict__ w,
                                                  const float* __restrict__ bcls,
                                                  float* __restrict__ out, int G) {
    const int g = blockIdx.x * 256 + threadIdx.x;
    if (g >= G) return;
    int s = gstart[g], e = gstart[g + 1];
    float invc = 1.0f / fmaxf((float)(e - s), 1.0f);
    float o0 = 0.f, o1 = 0.f, o2 = 0.f, o3 = 0.f;
    const float* gr = gsum + (size_t)g * 64;
#pragma unroll 8
    for (int hh = 0; hh < 64; ++hh) {
        float mm = gr[hh] * invc;
        float4 wr = *(const float4*)&w[hh * 4];
        o0 += mm * wr.x;
        o1 += mm * wr.y;
        o2 += mm * wr.z;
        o3 += mm * wr.w;
    }
    float4 o = make_float4(o0 + bcls[0], o1 + bcls[1], o2 + bcls[2], o3 + bcls[3]);
    *(float4*)&out[g * 4] = o;
}

extern "C" void kernel_launch(void* const* d_in, const int* in_sizes, int n_in,
                              void* d_out, int out_size, void* d_ws, size_t ws_size,
                              hipStream_t stream) {
    const float* x        = (const float*)d_in[0];
    const int* edge_index = (const int*)d_in[1];
    const int* edge_type  = (const int*)d_in[2];
    const int* batch      = (const int*)d_in[3];
    const float* basis1 = (const float*)d_in[4];
    const float* comp1  = (const float*)d_in[5];
    const float* root1  = (const float*)d_in[6];
    const float* bias1  = (const float*)d_in[7];
    const float* basis2 = (const float*)d_in[8];
    const float* comp2  = (const float*)d_in[9];
    const float* root2  = (const float*)d_in[10];
    const float* bias2  = (const float*)d_in[11];
    const float* clas_w = (const float*)d_in[12];
    const float* clas_b = (const float*)d_in[13];

    const int N = in_sizes[0] / 64;
    const int E = in_sizes[2];
    const int G = out_size / 4;
    const int* src = edge_index;
    const int* dst = edge_index + E;
    const int nbuck = (N + 255) >> 8;
    const int build_blocks = (N + 31) / 32;
    const int read_blocks  = (N + 31) / 32;

    char* base = (char*)d_ws;
    size_t off = 0;
    auto carve = [&](size_t bytes) { void* p = base + off; off = (off + bytes + 15) & ~(size_t)15; return p; };
    int*   cur     = (int*)carve(sizeof(int) * 256);
    float* gsum    = (float*)carve(sizeof(float) * (size_t)G * HH);
    int*   gstart  = (int*)carve(sizeof(int) * ((size_t)G + 1));
    int*   tmp     = (int*)carve(sizeof(int) * (size_t)nbuck * CAP);
    int4*  rp4g    = (int4*)carve(sizeof(int4) * (size_t)N);
    int*   kendg   = (int*)carve(sizeof(int) * (size_t)N);
    int*   eidxg   = (int*)carve(sizeof(int) * (size_t)build_blocks * VCAP);
    short* W1t     = (short*)carve(sizeof(short) * LWN);
    short* W2t     = (short*)carve(sizeof(short) * LWN);
    short* Xb1     = (short*)carve(sizeof(short) * (size_t)N * 64);
    short* H1      = (short*)carve(sizeof(short) * (size_t)N * 64);
    float* gout    = (float*)d_out;

    const int ebl = (E + EPB - 1) / EPB;
    const int wbl = (2 * LWN + 255) / 256;
    const int nb  = (N + 255) / 256;
    const int gzb = (G * (HH / 4) + 255) / 256;
    const int cvb = (N * 64 / 4 + 255) / 256;
    const int work_blocks = ebl + wbl + nb + gzb + cvb;

    hipMemsetAsync(cur, 0, sizeof(int) * 256, stream);

    work_kernel<<<work_blocks, 256, 0, stream>>>(
        src, dst, edge_type, E, cur, tmp,
        basis1, comp1, root1, basis2, comp2, root2, W1t, W2t,
        batch, gstart, N, G, x, Xb1, gsum, ebl, wbl, nb, gzb);

    layer_build_kernel<<<build_blocks, 256, 0, stream>>>(
        cur, tmp, Xb1, W1t, bias1, H1, N, rp4g, kendg, eidxg);
    layer_read_kernel<<<read_blocks, 256, 0, stream>>>(
        rp4g, kendg, eidxg, H1, W2t, bias2, N, batch, gsum);

    cls_kernel<<<(G + 255) / 256, 256, 0, stream>>>(
        gsum, gstart, clas_w, clas_b, gout, G);
}